// Round 16
// baseline (166.374 us; speedup 1.0000x reference)
//
#include <hip/hip_runtime.h>
#include <hip/hip_fp16.h>

typedef __fp16 h2_t __attribute__((ext_vector_type(2)));
typedef _Float16 f16x8 __attribute__((ext_vector_type(8)));
typedef float f32x4 __attribute__((ext_vector_type(4)));
typedef unsigned int uint32;

#define S_DIM 8192
#define B_DIM 8192
#define Q_DIM 64
#define A_DIM 1024
#define H_DIM 64
#define N_GATES 576

#define MT 64                  // rows per m-tile (4 waves x 16)
#define LMT 4                  // m-tiles per persistent block
#define KSPLIT 8
#define KC (S_DIM / KSPLIT)    // 1024 k per block
#define BK 32                  // k per staged step (one MFMA k-tile)
#define NST (LMT * KC / BK)    // 128 total steps per block
#define NCHUNK 4
#define CHUNK (N_GATES / NCHUNK)   // 144

__device__ __forceinline__ uint32 pk_f16(float x, float y) {
    h2_t h = __builtin_amdgcn_cvt_pkrtz(x, y);
    return __builtin_bit_cast(uint32, h);
}

__device__ __forceinline__ f32x4 mfma16(uint4 a, uint4 b, f32x4 c) {
    return __builtin_amdgcn_mfma_f32_16x16x32_f16(
        __builtin_bit_cast(f16x8, a), __builtin_bit_cast(f16x8, b), c, 0, 0, 0);
}

// 16-B global->LDS DMA; lane i lands at base + i*16
__device__ __forceinline__ void gload_lds16(const float* g, float* lds) {
    __builtin_amdgcn_global_load_lds(
        (const __attribute__((address_space(1))) void*)g,
        (__attribute__((address_space(3))) void*)lds, 16, 0, 0);
}

// k_pre: one launch for all input-only prep.
__global__ void k_pre(const float* __restrict__ encw, uint4* __restrict__ bpack,
                      const float* __restrict__ w1, const float* __restrict__ mo,
                      float* __restrict__ WM) {
    const int bid = blockIdx.x;
    const int t   = threadIdx.x;
    if (bid < 256) {
        const int gid  = bid * 256 + t;                 // 65536 total
        const int lane = gid & 63;
        const int nt   = (gid >> 6) & 3;
        const int kt   = gid >> 8;                      // 0..255
        const int n = nt * 16 + (lane & 15);
        const int k = kt * 32 + (lane >> 4) * 8;
        const float* p = encw + (size_t)n * S_DIM + k;
        float4 x0 = *(const float4*)p;
        float4 x1 = *(const float4*)(p + 4);
        uint4 r;
        r.x = pk_f16(x0.x, x0.y);
        r.y = pk_f16(x0.z, x0.w);
        r.z = pk_f16(x1.x, x1.y);
        r.w = pk_f16(x1.z, x1.w);
        bpack[gid] = r;
    } else {
        __shared__ float red[4][64];
        const int j    = bid - 256;                     // 0..63
        const int lane = t & 63;
        const int wv   = t >> 6;                        // 0..3
        const float* w1r = w1 + (size_t)j * A_DIM + wv * 256;
        const float* mop = mo + (size_t)wv * 256 * 128 + lane * 2;
        float acc = 0.f;
#pragma unroll 8
        for (int a = 0; a < 256; ++a)
            acc = fmaf(w1r[a], mop[(size_t)a * 128], acc);
        red[wv][lane] = acc;
        __syncthreads();
        if (t < 64)
            WM[(size_t)j * 64 + t] = red[0][t] + red[1][t] + red[2][t] + red[3][t];
    }
}

// K1: PERSISTENT BLOCKS (1/CU): B-range (128 KB) preloaded into LDS ONCE,
// then 4 m-tiles x 32 steps with the r15 A-ring (3 bufs, both-sides swizzle,
// counted vmcnt, DMA issued 2 steps ahead). B global traffic: 128 -> 32 MB.
__global__ __launch_bounds__(256, 1) void k_gemm(
        const float* __restrict__ state, const uint4* __restrict__ bpack,
        float* __restrict__ partial) {
    __shared__ __align__(16) float As[3][MT * BK];      // 3 x 8 KB
    __shared__ __align__(16) uint4 Bs[(KC / 32) * 256]; // 32 ktiles x 4 nt x 64 = 128 KB
    const int t  = threadIdx.x;
    const int w  = t >> 6;
    const int l  = t & 63;
    const int m0b = blockIdx.x * (MT * LMT);            // 256 rows per block
    const int ks  = blockIdx.y;
    const int k0  = ks * KC;

    // compute-side coords (HW-validated A-frag mapping)
    const int fr = w * 16 + (l & 15);    // row in m-tile
    const int fx = fr & 7;               // read-side swizzle key (8 slots/row)
    const int g2 = l >> 4;               // k-group 0..3

    // ---- B preload: 128 chunks of 1 KB; wave w takes chunks w*32..w*32+31
    {
        const uint4* pbsrc = bpack + (size_t)(k0 >> 5) * 256;
#pragma unroll 4
        for (int c = 0; c < 32; ++c) {
            const int ch = w * 32 + c;
            gload_lds16((const float*)(pbsrc + ch * 64 + l), (float*)&Bs[ch * 64]);
        }
    }

    // A DMA for global step S (m-tile S/32, k-tile S%32): wave w covers rows
    // 16w..16w+15 via 2 calls; lane l -> row j*8+(l>>3), LDS slot (l&7),
    // global slot (l&7)^(l>>3)  (both-sides swizzle, r15-verified)
#define DMA(BUF, S) do { \
        const int mt_ = (S) >> 5; \
        const int kf_ = ((S) & 31) * BK; \
        _Pragma("unroll") \
        for (int i = 0; i < 2; ++i) { \
            const int j_ = 2 * w + i; \
            const int rl = j_ * 8 + (l >> 3); \
            const int ss = (l & 7) ^ (l >> 3); \
            const float* gp = state + (size_t)(m0b + mt_ * MT + rl) * S_DIM + k0 + kf_ + ss * 4; \
            gload_lds16(gp, &As[BUF][j_ * 256]); \
        } } while (0)

    f32x4 acc[4] = {};

    DMA(0, 0);
    DMA(1, 1);
    // all 128 B chunks done (A steps 0,1 may stay in flight)
    asm volatile("s_waitcnt vmcnt(4)" ::: "memory");
    __builtin_amdgcn_s_barrier();

    int buf = 0;
    for (int s = 0; s < NST; ++s) {
        if (s < NST - 2) {
            asm volatile("s_waitcnt vmcnt(2)" ::: "memory");   // own step-s pair landed
        } else {
            asm volatile("s_waitcnt vmcnt(0)" ::: "memory");
        }
        __builtin_amdgcn_s_barrier();
        __builtin_amdgcn_sched_barrier(0);
        if (s + 2 < NST) {
            const int ib = (buf == 0) ? 2 : buf - 1;           // (s+2)%3
            DMA(ib, s + 2);
        }
        // compute step s from As[buf] + Bs[ktile]
        {
            const int kt = s & 31;
            const int b0 = fr * BK;
            const float4 f0 = *(const float4*)&As[buf][b0 + (((2 * g2 + 0) ^ fx) << 2)];
            const float4 f1 = *(const float4*)&As[buf][b0 + (((2 * g2 + 1) ^ fx) << 2)];
            uint4 af;
            af.x = pk_f16(f0.x, f0.y); af.y = pk_f16(f0.z, f0.w);
            af.z = pk_f16(f1.x, f1.y); af.w = pk_f16(f1.z, f1.w);
            const uint4 bf0 = Bs[kt * 256 + 0 * 64 + l];
            const uint4 bf1 = Bs[kt * 256 + 1 * 64 + l];
            const uint4 bf2 = Bs[kt * 256 + 2 * 64 + l];
            const uint4 bf3 = Bs[kt * 256 + 3 * 64 + l];
            acc[0] = mfma16(af, bf0, acc[0]);
            acc[1] = mfma16(af, bf1, acc[1]);
            acc[2] = mfma16(af, bf2, acc[2]);
            acc[3] = mfma16(af, bf3, acc[3]);
        }
        // m-tile boundary: flush accumulators
        if ((s & 31) == 31) {
            const int mt = s >> 5;
            float* pc = partial + (size_t)ks * (B_DIM * Q_DIM);
            const int mr = m0b + mt * MT + w * 16 + (l >> 4) * 4;
            const int nc = l & 15;
#pragma unroll
            for (int nt = 0; nt < 4; ++nt) {
#pragma unroll
                for (int r = 0; r < 4; ++r)
                    pc[(size_t)(mr + r) * Q_DIM + nt * 16 + nc] = acc[nt][r];
                acc[nt] = (f32x4){0.f, 0.f, 0.f, 0.f};
            }
        }
        buf = (buf == 2) ? 0 : buf + 1;
    }
#undef DMA
}

// K2: sum partials + bias; softmax over q; per-block column sums
__global__ void k_softmax(const float* __restrict__ partial,
                          const float* __restrict__ encb,
                          float* __restrict__ colsum_parts) {
    __shared__ float red[4][64];
    const int lane = threadIdx.x & 63;
    const int wv   = threadIdx.x >> 6;
    const float eb = encb[lane];
    float accq = 0.f;
    for (int i = 0; i < 8; ++i) {
        const int r = blockIdx.x * 32 + i * 4 + wv;
        float x = eb;
#pragma unroll
        for (int ks = 0; ks < KSPLIT; ++ks)
            x += partial[(size_t)ks * (B_DIM * Q_DIM) + (size_t)r * Q_DIM + lane];
        float m = x;
        for (int o = 32; o > 0; o >>= 1) m = fmaxf(m, __shfl_xor(m, o));
        float e = __expf(x - m);
        float s = e;
        for (int o = 32; o > 0; o >>= 1) s += __shfl_xor(s, o);
        accq += e / s;
    }
    red[wv][lane] = accq;
    __syncthreads();
    if (threadIdx.x < 64) {
        colsum_parts[blockIdx.x * 64 + lane] =
            red[0][lane] + red[1][lane] + red[2][lane] + red[3][lane];
    }
}

// k_final: 256 blocks; redundant tail per block
__global__ void k_final(const float* __restrict__ colsum_parts,
                        const float* __restrict__ qp,
                        const float* __restrict__ WM,
                        const float* __restrict__ b1,
                        const float* __restrict__ w2, const float* __restrict__ b2,
                        float* __restrict__ out) {
    __shared__ float red[4][64];
    __shared__ float t0[64];
    __shared__ float cs[N_GATES], ss[N_GATES];
    __shared__ float pA[NCHUNK][64];
    __shared__ float pB[2][64];
    __shared__ float fv[64];
    __shared__ float gv[64];
    __shared__ float hl[64];
    const int t    = threadIdx.x;          // 256
    const int lane = t & 63;
    const int wv   = t >> 6;               // 0..3

    for (int g = t; g < N_GATES; g += 256) {
        float th = qp[g] * 0.5f;
        cs[g] = __cosf(th);
        ss[g] = __sinf(th);
    }
    {
        float c = 0.f;
#pragma unroll
        for (int i = 0; i < 64; ++i)
            c += colsum_parts[(size_t)(wv * 64 + i) * 64 + lane];
        red[wv][lane] = c;
    }
    __syncthreads();
    if (t < 64)
        t0[t] = red[0][t] + red[1][t] + red[2][t] + red[3][t];
    {
        float p = (lane == 0) ? 1.f : 0.f;
        const int g0 = wv * CHUNK;
        for (int g = 0; g < CHUNK; ++g) {
            float prev = __shfl(p, (lane + 63) & 63);
            p = fmaf(cs[g0 + g], p, ss[g0 + g] * prev);
        }
        pA[wv][lane] = p;
    }
    __syncthreads();
    if (wv < 2) {
        float r = 0.f;
        for (int i = 0; i < 64; ++i)
            r += pA[2 * wv][i] * pA[2 * wv + 1][(lane - i) & 63];
        pB[wv][lane] = r;
    }
    __syncthreads();
    if (wv == 0) {
        float r = 0.f;
        for (int i = 0; i < 64; ++i)
            r += pB[0][i] * pB[1][(lane - i) & 63];
        fv[lane] = r;
    }
    __syncthreads();
    if (wv == 0) {
        float r = 0.f;
        for (int i = 0; i < 64; ++i)
            r += fv[i] * t0[(lane - i) & 63];
        gv[lane] = r;
    }
    __syncthreads();
    if (t < 64) {
        float v = 0.f;
        const float* wr = WM + (size_t)t * 64;
#pragma unroll
        for (int q = 0; q < 64; ++q)
            v = fmaf(wr[q], gv[q], v);
        hl[t] = fmaxf(v + b1[t], 0.f);
    }
    __syncthreads();
    const int a = blockIdx.x * 4 + wv;
    float v = w2[(size_t)a * H_DIM + lane] * hl[lane];
    for (int o = 32; o > 0; o >>= 1) v += __shfl_xor(v, o);
    if (lane == 0) out[a] = v + b2[a];
}

extern "C" void kernel_launch(void* const* d_in, const int* in_sizes, int n_in,
                              void* d_out, int out_size, void* d_ws, size_t ws_size,
                              hipStream_t stream) {
    const float* state = (const float*)d_in[0];
    const float* encw  = (const float*)d_in[1];
    const float* encb  = (const float*)d_in[2];
    const float* qp    = (const float*)d_in[3];
    const float* mo    = (const float*)d_in[4];
    const float* w1    = (const float*)d_in[5];
    const float* b1    = (const float*)d_in[6];
    const float* w2    = (const float*)d_in[7];
    const float* b2    = (const float*)d_in[8];
    float* out = (float*)d_out;

    float* ws           = (float*)d_ws;
    float* colsum_parts = ws;                              // 16384 floats
    float* partial      = ws + 16384;                      // 8*524288 (16 MB)
    float* WM           = partial + (size_t)KSPLIT * B_DIM * Q_DIM;  // 4096
    uint4* bpack        = (uint4*)(WM + 4096);             // 65536 uint4 (1 MB)

    k_pre<<<dim3(320), dim3(256), 0, stream>>>(encw, bpack, w1, mo, WM);
    k_gemm<<<dim3(B_DIM / (MT * LMT), KSPLIT), dim3(256), 0, stream>>>(state, bpack, partial);
    k_softmax<<<dim3(256), dim3(256), 0, stream>>>(partial, encb, colsum_parts);
    k_final<<<dim3(256), dim3(256), 0, stream>>>(colsum_parts, qp, WM, b1, w2, b2, out);
}

// Round 17
// 104.947 us; speedup vs baseline: 1.5853x; 1.5853x over previous
//
#include <hip/hip_runtime.h>
#include <hip/hip_fp16.h>

typedef __fp16 h2_t __attribute__((ext_vector_type(2)));
typedef _Float16 f16x8 __attribute__((ext_vector_type(8)));
typedef float f32x4 __attribute__((ext_vector_type(4)));
typedef unsigned int uint32;

#define S_DIM 8192
#define B_DIM 8192
#define Q_DIM 64
#define A_DIM 1024
#define H_DIM 64
#define N_GATES 576

#define MT 64                  // rows per block (4 waves x 16 rows compute)
#define KSPLIT 16
#define KC (S_DIM / KSPLIT)    // 512 k per block
#define BK 32                  // k per staged step (one MFMA k-tile)
#define NSTEP (KC / BK)        // 16
#define NCHUNK 4
#define CHUNK (N_GATES / NCHUNK)   // 144

__device__ __forceinline__ uint32 pk_f16(float x, float y) {
    h2_t h = __builtin_amdgcn_cvt_pkrtz(x, y);
    return __builtin_bit_cast(uint32, h);
}

__device__ __forceinline__ f32x4 mfma16(uint4 a, uint4 b, f32x4 c) {
    return __builtin_amdgcn_mfma_f32_16x16x32_f16(
        __builtin_bit_cast(f16x8, a), __builtin_bit_cast(f16x8, b), c, 0, 0, 0);
}

// 16-B global->LDS DMA (no VGPR round trip); lane i lands at base + i*16
__device__ __forceinline__ void gload_lds16(const float* g, float* lds) {
    __builtin_amdgcn_global_load_lds(
        (const __attribute__((address_space(1))) void*)g,
        (__attribute__((address_space(3))) void*)lds, 16, 0, 0);
}

// k_pre: one launch for all input-only prep.
__global__ void k_pre(const float* __restrict__ encw, uint4* __restrict__ bpack,
                      const float* __restrict__ w1, const float* __restrict__ mo,
                      float* __restrict__ WM) {
    const int bid = blockIdx.x;
    const int t   = threadIdx.x;
    if (bid < 256) {
        const int gid  = bid * 256 + t;                 // 65536 total
        const int lane = gid & 63;
        const int nt   = (gid >> 6) & 3;
        const int kt   = gid >> 8;                      // 0..255
        const int n = nt * 16 + (lane & 15);
        const int k = kt * 32 + (lane >> 4) * 8;
        const float* p = encw + (size_t)n * S_DIM + k;
        float4 x0 = *(const float4*)p;
        float4 x1 = *(const float4*)(p + 4);
        uint4 r;
        r.x = pk_f16(x0.x, x0.y);
        r.y = pk_f16(x0.z, x0.w);
        r.z = pk_f16(x1.x, x1.y);
        r.w = pk_f16(x1.z, x1.w);
        bpack[gid] = r;
    } else {
        __shared__ float red[4][64];
        const int j    = bid - 256;                     // 0..63
        const int lane = t & 63;
        const int wv   = t >> 6;                        // 0..3
        const float* w1r = w1 + (size_t)j * A_DIM + wv * 256;
        const float* mop = mo + (size_t)wv * 256 * 128 + lane * 2;
        float acc = 0.f;
#pragma unroll 8
        for (int a = 0; a < 256; ++a)
            acc = fmaf(w1r[a], mop[(size_t)a * 128], acc);
        red[wv][lane] = acc;
        __syncthreads();
        if (t < 64)
            WM[(size_t)j * 64 + t] = red[0][t] + red[1][t] + red[2][t] + red[3][t];
    }
}

// K1: r15-verified structure (B de-dup via LDS, 3-ring, both-sides swizzle,
// counted vmcnt). ONLY change: KSPLIT 8->16 (2048 blocks, 2 generations/CU)
// to break lockstep phases and overlap block tails.
__global__ __launch_bounds__(256, 4) void k_gemm(
        const float* __restrict__ state, const uint4* __restrict__ bpack,
        float* __restrict__ partial) {
    __shared__ __align__(16) float As[3][MT * BK];      // 3 x 8 KB
    __shared__ __align__(16) float Bs[3][4 * 256];      // 3 x 4 KB
    const int t  = threadIdx.x;
    const int w  = t >> 6;
    const int l  = t & 63;
    const int m0 = blockIdx.x * MT;
    const int ks = blockIdx.y;
    const int k0 = ks * KC;

    // compute-side coords (HW-validated A-frag mapping)
    const int fr = w * 16 + (l & 15);    // row in tile
    const int fx = fr & 7;               // read-side swizzle key (8 slots/row)
    const int g2 = l >> 4;               // k-group 0..3

#define DMA(BUF, S) do { \
        _Pragma("unroll") \
        for (int i = 0; i < 2; ++i) { \
            const int j_ = 2 * w + i; \
            const int rl = j_ * 8 + (l >> 3); \
            const int ss = (l & 7) ^ (l >> 3); \
            const float* gp = state + (size_t)(m0 + rl) * S_DIM + k0 + (S) * BK + ss * 4; \
            gload_lds16(gp, &As[BUF][j_ * 256]); \
        } \
        { \
            const float* gb = (const float*)(bpack + (size_t)((k0 >> 5) + (S)) * 256 + w * 64 + l); \
            gload_lds16(gb, &Bs[BUF][w * 256]); \
        } } while (0)

#define COMPUTE(BUF, S) do { \
        const int b0 = fr * BK; \
        const float4 f0 = *(const float4*)&As[BUF][b0 + (((2 * g2 + 0) ^ fx) << 2)]; \
        const float4 f1 = *(const float4*)&As[BUF][b0 + (((2 * g2 + 1) ^ fx) << 2)]; \
        uint4 af; \
        af.x = pk_f16(f0.x, f0.y); af.y = pk_f16(f0.z, f0.w); \
        af.z = pk_f16(f1.x, f1.y); af.w = pk_f16(f1.z, f1.w); \
        const uint4 bf0 = *(const uint4*)&Bs[BUF][0 * 256 + l * 4]; \
        const uint4 bf1 = *(const uint4*)&Bs[BUF][1 * 256 + l * 4]; \
        const uint4 bf2 = *(const uint4*)&Bs[BUF][2 * 256 + l * 4]; \
        const uint4 bf3 = *(const uint4*)&Bs[BUF][3 * 256 + l * 4]; \
        acc[0] = mfma16(af, bf0, acc[0]); \
        acc[1] = mfma16(af, bf1, acc[1]); \
        acc[2] = mfma16(af, bf2, acc[2]); \
        acc[3] = mfma16(af, bf3, acc[3]); } while (0)

    f32x4 acc[4] = {};

    DMA(0, 0);          // prologue: 2 steps in flight
    DMA(1, 1);

    int buf = 0, ibuf = 2;
    for (int s = 0; s < NSTEP - 1; ++s) {
        // own 3 DMAs for buf landed; next step's 3 stay in flight
        asm volatile("s_waitcnt vmcnt(3)" ::: "memory");
        __builtin_amdgcn_s_barrier();        // all waves' buf data in LDS
        __builtin_amdgcn_sched_barrier(0);
        if (s + 2 < NSTEP) DMA(ibuf, s + 2); // WAR-safe: ibuf read 2 iters ago
        COMPUTE(buf, s);
        buf  = (buf  == 2) ? 0 : buf  + 1;
        ibuf = (ibuf == 2) ? 0 : ibuf + 1;
    }
    asm volatile("s_waitcnt vmcnt(0)" ::: "memory");
    __builtin_amdgcn_s_barrier();
    __builtin_amdgcn_sched_barrier(0);
    COMPUTE(buf, NSTEP - 1);
#undef DMA
#undef COMPUTE

    // C/D: col = lane&15, row = (lane>>4)*4 + reg  (verified mapping)
    float* pc = partial + (size_t)ks * (B_DIM * Q_DIM);
    const int mr = m0 + w * 16 + (l >> 4) * 4;
    const int nc = l & 15;
#pragma unroll
    for (int nt = 0; nt < 4; ++nt)
#pragma unroll
        for (int r = 0; r < 4; ++r)
            pc[(size_t)(mr + r) * Q_DIM + nt * 16 + nc] = acc[nt][r];
}

// K2: sum partials + bias; softmax over q; per-block column sums
__global__ void k_softmax(const float* __restrict__ partial,
                          const float* __restrict__ encb,
                          float* __restrict__ colsum_parts) {
    __shared__ float red[4][64];
    const int lane = threadIdx.x & 63;
    const int wv   = threadIdx.x >> 6;
    const float eb = encb[lane];
    float accq = 0.f;
    for (int i = 0; i < 8; ++i) {
        const int r = blockIdx.x * 32 + i * 4 + wv;
        float x = eb;
#pragma unroll
        for (int ks = 0; ks < KSPLIT; ++ks)
            x += partial[(size_t)ks * (B_DIM * Q_DIM) + (size_t)r * Q_DIM + lane];
        float m = x;
        for (int o = 32; o > 0; o >>= 1) m = fmaxf(m, __shfl_xor(m, o));
        float e = __expf(x - m);
        float s = e;
        for (int o = 32; o > 0; o >>= 1) s += __shfl_xor(s, o);
        accq += e / s;
    }
    red[wv][lane] = accq;
    __syncthreads();
    if (threadIdx.x < 64) {
        colsum_parts[blockIdx.x * 64 + lane] =
            red[0][lane] + red[1][lane] + red[2][lane] + red[3][lane];
    }
}

// k_final: 256 blocks; redundant tail per block
__global__ void k_final(const float* __restrict__ colsum_parts,
                        const float* __restrict__ qp,
                        const float* __restrict__ WM,
                        const float* __restrict__ b1,
                        const float* __restrict__ w2, const float* __restrict__ b2,
                        float* __restrict__ out) {
    __shared__ float red[4][64];
    __shared__ float t0[64];
    __shared__ float cs[N_GATES], ss[N_GATES];
    __shared__ float pA[NCHUNK][64];
    __shared__ float pB[2][64];
    __shared__ float fv[64];
    __shared__ float gv[64];
    __shared__ float hl[64];
    const int t    = threadIdx.x;          // 256
    const int lane = t & 63;
    const int wv   = t >> 6;               // 0..3

    for (int g = t; g < N_GATES; g += 256) {
        float th = qp[g] * 0.5f;
        cs[g] = __cosf(th);
        ss[g] = __sinf(th);
    }
    {
        float c = 0.f;
#pragma unroll
        for (int i = 0; i < 64; ++i)
            c += colsum_parts[(size_t)(wv * 64 + i) * 64 + lane];
        red[wv][lane] = c;
    }
    __syncthreads();
    if (t < 64)
        t0[t] = red[0][t] + red[1][t] + red[2][t] + red[3][t];
    {
        float p = (lane == 0) ? 1.f : 0.f;
        const int g0 = wv * CHUNK;
        for (int g = 0; g < CHUNK; ++g) {
            float prev = __shfl(p, (lane + 63) & 63);
            p = fmaf(cs[g0 + g], p, ss[g0 + g] * prev);
        }
        pA[wv][lane] = p;
    }
    __syncthreads();
    if (wv < 2) {
        float r = 0.f;
        for (int i = 0; i < 64; ++i)
            r += pA[2 * wv][i] * pA[2 * wv + 1][(lane - i) & 63];
        pB[wv][lane] = r;
    }
    __syncthreads();
    if (wv == 0) {
        float r = 0.f;
        for (int i = 0; i < 64; ++i)
            r += pB[0][i] * pB[1][(lane - i) & 63];
        fv[lane] = r;
    }
    __syncthreads();
    if (wv == 0) {
        float r = 0.f;
        for (int i = 0; i < 64; ++i)
            r += fv[i] * t0[(lane - i) & 63];
        gv[lane] = r;
    }
    __syncthreads();
    if (t < 64) {
        float v = 0.f;
        const float* wr = WM + (size_t)t * 64;
#pragma unroll
        for (int q = 0; q < 64; ++q)
            v = fmaf(wr[q], gv[q], v);
        hl[t] = fmaxf(v + b1[t], 0.f);
    }
    __syncthreads();
    const int a = blockIdx.x * 4 + wv;
    float v = w2[(size_t)a * H_DIM + lane] * hl[lane];
    for (int o = 32; o > 0; o >>= 1) v += __shfl_xor(v, o);
    if (lane == 0) out[a] = v + b2[a];
}

extern "C" void kernel_launch(void* const* d_in, const int* in_sizes, int n_in,
                              void* d_out, int out_size, void* d_ws, size_t ws_size,
                              hipStream_t stream) {
    const float* state = (const float*)d_in[0];
    const float* encw  = (const float*)d_in[1];
    const float* encb  = (const float*)d_in[2];
    const float* qp    = (const float*)d_in[3];
    const float* mo    = (const float*)d_in[4];
    const float* w1    = (const float*)d_in[5];
    const float* b1    = (const float*)d_in[6];
    const float* w2    = (const float*)d_in[7];
    const float* b2    = (const float*)d_in[8];
    float* out = (float*)d_out;

    float* ws           = (float*)d_ws;
    float* colsum_parts = ws;                              // 16384 floats
    float* partial      = ws + 16384;                      // 16*524288 (32 MB)
    float* WM           = partial + (size_t)KSPLIT * B_DIM * Q_DIM;  // 4096
    uint4* bpack        = (uint4*)(WM + 4096);             // 65536 uint4 (1 MB)

    k_pre<<<dim3(320), dim3(256), 0, stream>>>(encw, bpack, w1, mo, WM);
    k_gemm<<<dim3(B_DIM / MT, KSPLIT), dim3(256), 0, stream>>>(state, bpack, partial);
    k_softmax<<<dim3(256), dim3(256), 0, stream>>>(partial, encb, colsum_parts);
    k_final<<<dim3(256), dim3(256), 0, stream>>>(colsum_parts, qp, WM, b1, w2, b2, out);
}

// Round 18
// 86.211 us; speedup vs baseline: 1.9299x; 1.2173x over previous
//
#include <hip/hip_runtime.h>
#include <hip/hip_fp16.h>

typedef __fp16 h2_t __attribute__((ext_vector_type(2)));
typedef _Float16 f16x8 __attribute__((ext_vector_type(8)));
typedef float f32x4 __attribute__((ext_vector_type(4)));
typedef unsigned int uint32;

#define S_DIM 8192
#define B_DIM 8192
#define Q_DIM 64
#define A_DIM 1024
#define H_DIM 64
#define N_GATES 576

#define MT 64                  // rows per block (4 waves x 16 rows compute)
#define KSPLIT 8
#define KC (S_DIM / KSPLIT)    // 1024 k per block
#define BK 32                  // k per staged step (one MFMA k-tile)
#define NSTEP (KC / BK)        // 32
#define NCHUNK 4
#define CHUNK (N_GATES / NCHUNK)   // 144

__device__ __forceinline__ uint32 pk_f16(float x, float y) {
    h2_t h = __builtin_amdgcn_cvt_pkrtz(x, y);
    return __builtin_bit_cast(uint32, h);
}

__device__ __forceinline__ f32x4 mfma16(uint4 a, uint4 b, f32x4 c) {
    return __builtin_amdgcn_mfma_f32_16x16x32_f16(
        __builtin_bit_cast(f16x8, a), __builtin_bit_cast(f16x8, b), c, 0, 0, 0);
}

// 16-B global->LDS DMA (no VGPR round trip); lane i lands at base + i*16
__device__ __forceinline__ void gload_lds16(const float* g, float* lds) {
    __builtin_amdgcn_global_load_lds(
        (const __attribute__((address_space(1))) void*)g,
        (__attribute__((address_space(3))) void*)lds, 16, 0, 0);
}

// k_pre: one launch for all input-only prep.
__global__ void k_pre(const float* __restrict__ encw, uint4* __restrict__ bpack,
                      const float* __restrict__ w1, const float* __restrict__ mo,
                      float* __restrict__ WM) {
    const int bid = blockIdx.x;
    const int t   = threadIdx.x;
    if (bid < 256) {
        const int gid  = bid * 256 + t;                 // 65536 total
        const int lane = gid & 63;
        const int nt   = (gid >> 6) & 3;
        const int kt   = gid >> 8;                      // 0..255
        const int n = nt * 16 + (lane & 15);
        const int k = kt * 32 + (lane >> 4) * 8;
        const float* p = encw + (size_t)n * S_DIM + k;
        float4 x0 = *(const float4*)p;
        float4 x1 = *(const float4*)(p + 4);
        uint4 r;
        r.x = pk_f16(x0.x, x0.y);
        r.y = pk_f16(x0.z, x0.w);
        r.z = pk_f16(x1.x, x1.y);
        r.w = pk_f16(x1.z, x1.w);
        bpack[gid] = r;
    } else {
        __shared__ float red[4][64];
        const int j    = bid - 256;                     // 0..63
        const int lane = t & 63;
        const int wv   = t >> 6;                        // 0..3
        const float* w1r = w1 + (size_t)j * A_DIM + wv * 256;
        const float* mop = mo + (size_t)wv * 256 * 128 + lane * 2;
        float acc = 0.f;
#pragma unroll 8
        for (int a = 0; a < 256; ++a)
            acc = fmaf(w1r[a], mop[(size_t)a * 128], acc);
        red[wv][lane] = acc;
        __syncthreads();
        if (t < 64)
            WM[(size_t)j * 64 + t] = red[0][t] + red[1][t] + red[2][t] + red[3][t];
    }
}

// K1: r15-verified structure (B de-dup via LDS, 3-ring, both-sides swizzle,
// counted vmcnt, 4 blocks/CU). Survived perturbation in 4 directions; kept.
__global__ __launch_bounds__(256, 4) void k_gemm(
        const float* __restrict__ state, const uint4* __restrict__ bpack,
        float* __restrict__ partial) {
    __shared__ __align__(16) float As[3][MT * BK];      // 3 x 8 KB
    __shared__ __align__(16) float Bs[3][4 * 256];      // 3 x 4 KB
    const int t  = threadIdx.x;
    const int w  = t >> 6;
    const int l  = t & 63;
    const int m0 = blockIdx.x * MT;
    const int ks = blockIdx.y;
    const int k0 = ks * KC;

    // compute-side coords (HW-validated A-frag mapping)
    const int fr = w * 16 + (l & 15);    // row in tile
    const int fx = fr & 7;               // read-side swizzle key (8 slots/row)
    const int g2 = l >> 4;               // k-group 0..3

    // A: call j (wave w does j=2w,2w+1) covers rows j*8..j*8+7; lane l ->
    // row j*8+(l>>3), LDS slot (l&7); global slot (l&7)^(l>>3) (both-sides).
    // B: wave w DMAs fragment chunk nt=w (1 KB, already fragment-ordered).
#define DMA(BUF, S) do { \
        _Pragma("unroll") \
        for (int i = 0; i < 2; ++i) { \
            const int j_ = 2 * w + i; \
            const int rl = j_ * 8 + (l >> 3); \
            const int ss = (l & 7) ^ (l >> 3); \
            const float* gp = state + (size_t)(m0 + rl) * S_DIM + k0 + (S) * BK + ss * 4; \
            gload_lds16(gp, &As[BUF][j_ * 256]); \
        } \
        { \
            const float* gb = (const float*)(bpack + (size_t)((k0 >> 5) + (S)) * 256 + w * 64 + l); \
            gload_lds16(gb, &Bs[BUF][w * 256]); \
        } } while (0)

#define COMPUTE(BUF, S) do { \
        const int b0 = fr * BK; \
        const float4 f0 = *(const float4*)&As[BUF][b0 + (((2 * g2 + 0) ^ fx) << 2)]; \
        const float4 f1 = *(const float4*)&As[BUF][b0 + (((2 * g2 + 1) ^ fx) << 2)]; \
        uint4 af; \
        af.x = pk_f16(f0.x, f0.y); af.y = pk_f16(f0.z, f0.w); \
        af.z = pk_f16(f1.x, f1.y); af.w = pk_f16(f1.z, f1.w); \
        const uint4 bf0 = *(const uint4*)&Bs[BUF][0 * 256 + l * 4]; \
        const uint4 bf1 = *(const uint4*)&Bs[BUF][1 * 256 + l * 4]; \
        const uint4 bf2 = *(const uint4*)&Bs[BUF][2 * 256 + l * 4]; \
        const uint4 bf3 = *(const uint4*)&Bs[BUF][3 * 256 + l * 4]; \
        acc[0] = mfma16(af, bf0, acc[0]); \
        acc[1] = mfma16(af, bf1, acc[1]); \
        acc[2] = mfma16(af, bf2, acc[2]); \
        acc[3] = mfma16(af, bf3, acc[3]); } while (0)

    f32x4 acc[4] = {};

    DMA(0, 0);          // prologue: 2 steps in flight
    DMA(1, 1);

    int buf = 0, ibuf = 2;
    for (int s = 0; s < NSTEP - 1; ++s) {
        // own 3 DMAs for buf landed; next step's 3 stay in flight
        asm volatile("s_waitcnt vmcnt(3)" ::: "memory");
        __builtin_amdgcn_s_barrier();        // all waves' buf data in LDS
        __builtin_amdgcn_sched_barrier(0);
        if (s + 2 < NSTEP) DMA(ibuf, s + 2); // WAR-safe: ibuf read 2 iters ago
        COMPUTE(buf, s);
        buf  = (buf  == 2) ? 0 : buf  + 1;
        ibuf = (ibuf == 2) ? 0 : ibuf + 1;
    }
    asm volatile("s_waitcnt vmcnt(0)" ::: "memory");
    __builtin_amdgcn_s_barrier();
    __builtin_amdgcn_sched_barrier(0);
    COMPUTE(buf, NSTEP - 1);
#undef DMA
#undef COMPUTE

    // C/D: col = lane&15, row = (lane>>4)*4 + reg  (verified mapping)
    float* pc = partial + (size_t)ks * (B_DIM * Q_DIM);
    const int mr = m0 + w * 16 + (l >> 4) * 4;
    const int nc = l & 15;
#pragma unroll
    for (int nt = 0; nt < 4; ++nt)
#pragma unroll
        for (int r = 0; r < 4; ++r)
            pc[(size_t)(mr + r) * Q_DIM + nt * 16 + nc] = acc[nt][r];
}

// K2: sum partials + bias; softmax over q; per-block column sums
__global__ void k_softmax(const float* __restrict__ partial,
                          const float* __restrict__ encb,
                          float* __restrict__ colsum_parts) {
    __shared__ float red[4][64];
    const int lane = threadIdx.x & 63;
    const int wv   = threadIdx.x >> 6;
    const float eb = encb[lane];
    float accq = 0.f;
    for (int i = 0; i < 8; ++i) {
        const int r = blockIdx.x * 32 + i * 4 + wv;
        float x = eb;
#pragma unroll
        for (int ks = 0; ks < KSPLIT; ++ks)
            x += partial[(size_t)ks * (B_DIM * Q_DIM) + (size_t)r * Q_DIM + lane];
        float m = x;
        for (int o = 32; o > 0; o >>= 1) m = fmaxf(m, __shfl_xor(m, o));
        float e = __expf(x - m);
        float s = e;
        for (int o = 32; o > 0; o >>= 1) s += __shfl_xor(s, o);
        accq += e / s;
    }
    red[wv][lane] = accq;
    __syncthreads();
    if (threadIdx.x < 64) {
        colsum_parts[blockIdx.x * 64 + lane] =
            red[0][lane] + red[1][lane] + red[2][lane] + red[3][lane];
    }
}

// k_final: 256 blocks; redundant tail per block
__global__ void k_final(const float* __restrict__ colsum_parts,
                        const float* __restrict__ qp,
                        const float* __restrict__ WM,
                        const float* __restrict__ b1,
                        const float* __restrict__ w2, const float* __restrict__ b2,
                        float* __restrict__ out) {
    __shared__ float red[4][64];
    __shared__ float t0[64];
    __shared__ float cs[N_GATES], ss[N_GATES];
    __shared__ float pA[NCHUNK][64];
    __shared__ float pB[2][64];
    __shared__ float fv[64];
    __shared__ float gv[64];
    __shared__ float hl[64];
    const int t    = threadIdx.x;          // 256
    const int lane = t & 63;
    const int wv   = t >> 6;               // 0..3

    for (int g = t; g < N_GATES; g += 256) {
        float th = qp[g] * 0.5f;
        cs[g] = __cosf(th);
        ss[g] = __sinf(th);
    }
    {
        float c = 0.f;
#pragma unroll
        for (int i = 0; i < 64; ++i)
            c += colsum_parts[(size_t)(wv * 64 + i) * 64 + lane];
        red[wv][lane] = c;
    }
    __syncthreads();
    if (t < 64)
        t0[t] = red[0][t] + red[1][t] + red[2][t] + red[3][t];
    {
        float p = (lane == 0) ? 1.f : 0.f;
        const int g0 = wv * CHUNK;
        for (int g = 0; g < CHUNK; ++g) {
            float prev = __shfl(p, (lane + 63) & 63);
            p = fmaf(cs[g0 + g], p, ss[g0 + g] * prev);
        }
        pA[wv][lane] = p;
    }
    __syncthreads();
    if (wv < 2) {
        float r = 0.f;
        for (int i = 0; i < 64; ++i)
            r += pA[2 * wv][i] * pA[2 * wv + 1][(lane - i) & 63];
        pB[wv][lane] = r;
    }
    __syncthreads();
    if (wv == 0) {
        float r = 0.f;
        for (int i = 0; i < 64; ++i)
            r += pB[0][i] * pB[1][(lane - i) & 63];
        fv[lane] = r;
    }
    __syncthreads();
    if (wv == 0) {
        float r = 0.f;
        for (int i = 0; i < 64; ++i)
            r += fv[i] * t0[(lane - i) & 63];
        gv[lane] = r;
    }
    __syncthreads();
    if (t < 64) {
        float v = 0.f;
        const float* wr = WM + (size_t)t * 64;
#pragma unroll
        for (int q = 0; q < 64; ++q)
            v = fmaf(wr[q], gv[q], v);
        hl[t] = fmaxf(v + b1[t], 0.f);
    }
    __syncthreads();
    const int a = blockIdx.x * 4 + wv;
    float v = w2[(size_t)a * H_DIM + lane] * hl[lane];
    for (int o = 32; o > 0; o >>= 1) v += __shfl_xor(v, o);
    if (lane == 0) out[a] = v + b2[a];
}

extern "C" void kernel_launch(void* const* d_in, const int* in_sizes, int n_in,
                              void* d_out, int out_size, void* d_ws, size_t ws_size,
                              hipStream_t stream) {
    const float* state = (const float*)d_in[0];
    const float* encw  = (const float*)d_in[1];
    const float* encb  = (const float*)d_in[2];
    const float* qp    = (const float*)d_in[3];
    const float* mo    = (const float*)d_in[4];
    const float* w1    = (const float*)d_in[5];
    const float* b1    = (const float*)d_in[6];
    const float* w2    = (const float*)d_in[7];
    const float* b2    = (const float*)d_in[8];
    float* out = (float*)d_out;

    float* ws           = (float*)d_ws;
    float* colsum_parts = ws;                              // 16384 floats
    float* partial      = ws + 16384;                      // 8*524288 (16 MB)
    float* WM           = partial + (size_t)KSPLIT * B_DIM * Q_DIM;  // 4096
    uint4* bpack        = (uint4*)(WM + 4096);             // 65536 uint4 (1 MB)

    k_pre<<<dim3(320), dim3(256), 0, stream>>>(encw, bpack, w1, mo, WM);
    k_gemm<<<dim3(B_DIM / MT, KSPLIT), dim3(256), 0, stream>>>(state, bpack, partial);
    k_softmax<<<dim3(256), dim3(256), 0, stream>>>(partial, encb, colsum_parts);
    k_final<<<dim3(256), dim3(256), 0, stream>>>(colsum_parts, qp, WM, b1, w2, b2, out);
}

// Round 19
// 81.378 us; speedup vs baseline: 2.0445x; 1.0594x over previous
//
#include <hip/hip_runtime.h>
#include <hip/hip_fp16.h>

typedef __fp16 h2_t __attribute__((ext_vector_type(2)));
typedef _Float16 f16x8 __attribute__((ext_vector_type(8)));
typedef float f32x4 __attribute__((ext_vector_type(4)));
typedef unsigned int uint32;

#define S_DIM 8192
#define B_DIM 8192
#define Q_DIM 64
#define A_DIM 1024
#define H_DIM 64
#define N_GATES 576

#define MT 64                  // rows per block (4 waves x 16 rows compute)
#define KSPLIT 8
#define KC (S_DIM / KSPLIT)    // 1024 k per block
#define BK 32                  // k per staged step (one MFMA k-tile)
#define NSTEP (KC / BK)        // 32
#define NCHUNK 4
#define CHUNK (N_GATES / NCHUNK)   // 144

__device__ __forceinline__ uint32 pk_f16(float x, float y) {
    h2_t h = __builtin_amdgcn_cvt_pkrtz(x, y);
    return __builtin_bit_cast(uint32, h);
}

__device__ __forceinline__ f32x4 mfma16(uint4 a, uint4 b, f32x4 c) {
    return __builtin_amdgcn_mfma_f32_16x16x32_f16(
        __builtin_bit_cast(f16x8, a), __builtin_bit_cast(f16x8, b), c, 0, 0, 0);
}

// 16-B global->LDS DMA (no VGPR round trip); lane i lands at base + i*16
__device__ __forceinline__ void gload_lds16(const float* g, float* lds) {
    __builtin_amdgcn_global_load_lds(
        (const __attribute__((address_space(1))) void*)g,
        (__attribute__((address_space(3))) void*)lds, 16, 0, 0);
}

// k_pre: one launch for all input-only prep.
__global__ void k_pre(const float* __restrict__ encw, uint4* __restrict__ bpack,
                      const float* __restrict__ w1, const float* __restrict__ mo,
                      float* __restrict__ WM) {
    const int bid = blockIdx.x;
    const int t   = threadIdx.x;
    if (bid < 256) {
        const int gid  = bid * 256 + t;                 // 65536 total
        const int lane = gid & 63;
        const int nt   = (gid >> 6) & 3;
        const int kt   = gid >> 8;                      // 0..255
        const int n = nt * 16 + (lane & 15);
        const int k = kt * 32 + (lane >> 4) * 8;
        const float* p = encw + (size_t)n * S_DIM + k;
        float4 x0 = *(const float4*)p;
        float4 x1 = *(const float4*)(p + 4);
        uint4 r;
        r.x = pk_f16(x0.x, x0.y);
        r.y = pk_f16(x0.z, x0.w);
        r.z = pk_f16(x1.x, x1.y);
        r.w = pk_f16(x1.z, x1.w);
        bpack[gid] = r;
    } else {
        __shared__ float red[4][64];
        const int j    = bid - 256;                     // 0..63
        const int lane = t & 63;
        const int wv   = t >> 6;                        // 0..3
        const float* w1r = w1 + (size_t)j * A_DIM + wv * 256;
        const float* mop = mo + (size_t)wv * 256 * 128 + lane * 2;
        float acc = 0.f;
#pragma unroll 8
        for (int a = 0; a < 256; ++a)
            acc = fmaf(w1r[a], mop[(size_t)a * 128], acc);
        red[wv][lane] = acc;
        __syncthreads();
        if (t < 64)
            WM[(size_t)j * 64 + t] = red[0][t] + red[1][t] + red[2][t] + red[3][t];
    }
}

// K1: r15-verified structure (B de-dup via LDS, 3-ring, both-sides swizzle,
// counted vmcnt, 4 blocks/CU). ONLY change vs r18: partials stored as f16
// (halves the partial write + softmax read traffic).
__global__ __launch_bounds__(256, 4) void k_gemm(
        const float* __restrict__ state, const uint4* __restrict__ bpack,
        __fp16* __restrict__ partial) {
    __shared__ __align__(16) float As[3][MT * BK];      // 3 x 8 KB
    __shared__ __align__(16) float Bs[3][4 * 256];      // 3 x 4 KB
    const int t  = threadIdx.x;
    const int w  = t >> 6;
    const int l  = t & 63;
    const int m0 = blockIdx.x * MT;
    const int ks = blockIdx.y;
    const int k0 = ks * KC;

    // compute-side coords (HW-validated A-frag mapping)
    const int fr = w * 16 + (l & 15);    // row in tile
    const int fx = fr & 7;               // read-side swizzle key (8 slots/row)
    const int g2 = l >> 4;               // k-group 0..3

    // A: call j (wave w does j=2w,2w+1) covers rows j*8..j*8+7; lane l ->
    // row j*8+(l>>3), LDS slot (l&7); global slot (l&7)^(l>>3) (both-sides).
    // B: wave w DMAs fragment chunk nt=w (1 KB, already fragment-ordered).
#define DMA(BUF, S) do { \
        _Pragma("unroll") \
        for (int i = 0; i < 2; ++i) { \
            const int j_ = 2 * w + i; \
            const int rl = j_ * 8 + (l >> 3); \
            const int ss = (l & 7) ^ (l >> 3); \
            const float* gp = state + (size_t)(m0 + rl) * S_DIM + k0 + (S) * BK + ss * 4; \
            gload_lds16(gp, &As[BUF][j_ * 256]); \
        } \
        { \
            const float* gb = (const float*)(bpack + (size_t)((k0 >> 5) + (S)) * 256 + w * 64 + l); \
            gload_lds16(gb, &Bs[BUF][w * 256]); \
        } } while (0)

#define COMPUTE(BUF, S) do { \
        const int b0 = fr * BK; \
        const float4 f0 = *(const float4*)&As[BUF][b0 + (((2 * g2 + 0) ^ fx) << 2)]; \
        const float4 f1 = *(const float4*)&As[BUF][b0 + (((2 * g2 + 1) ^ fx) << 2)]; \
        uint4 af; \
        af.x = pk_f16(f0.x, f0.y); af.y = pk_f16(f0.z, f0.w); \
        af.z = pk_f16(f1.x, f1.y); af.w = pk_f16(f1.z, f1.w); \
        const uint4 bf0 = *(const uint4*)&Bs[BUF][0 * 256 + l * 4]; \
        const uint4 bf1 = *(const uint4*)&Bs[BUF][1 * 256 + l * 4]; \
        const uint4 bf2 = *(const uint4*)&Bs[BUF][2 * 256 + l * 4]; \
        const uint4 bf3 = *(const uint4*)&Bs[BUF][3 * 256 + l * 4]; \
        acc[0] = mfma16(af, bf0, acc[0]); \
        acc[1] = mfma16(af, bf1, acc[1]); \
        acc[2] = mfma16(af, bf2, acc[2]); \
        acc[3] = mfma16(af, bf3, acc[3]); } while (0)

    f32x4 acc[4] = {};

    DMA(0, 0);          // prologue: 2 steps in flight
    DMA(1, 1);

    int buf = 0, ibuf = 2;
    for (int s = 0; s < NSTEP - 1; ++s) {
        // own 3 DMAs for buf landed; next step's 3 stay in flight
        asm volatile("s_waitcnt vmcnt(3)" ::: "memory");
        __builtin_amdgcn_s_barrier();        // all waves' buf data in LDS
        __builtin_amdgcn_sched_barrier(0);
        if (s + 2 < NSTEP) DMA(ibuf, s + 2); // WAR-safe: ibuf read 2 iters ago
        COMPUTE(buf, s);
        buf  = (buf  == 2) ? 0 : buf  + 1;
        ibuf = (ibuf == 2) ? 0 : ibuf + 1;
    }
    asm volatile("s_waitcnt vmcnt(0)" ::: "memory");
    __builtin_amdgcn_s_barrier();
    __builtin_amdgcn_sched_barrier(0);
    COMPUTE(buf, NSTEP - 1);
#undef DMA
#undef COMPUTE

    // C/D: col = lane&15, row = (lane>>4)*4 + reg  (verified mapping)
    __fp16* pc = partial + (size_t)ks * (B_DIM * Q_DIM);
    const int mr = m0 + w * 16 + (l >> 4) * 4;
    const int nc = l & 15;
#pragma unroll
    for (int nt = 0; nt < 4; ++nt)
#pragma unroll
        for (int r = 0; r < 4; ++r)
            pc[(size_t)(mr + r) * Q_DIM + nt * 16 + nc] = (__fp16)acc[nt][r];
}

// K2: sum f16 partials + bias; softmax over q; per-block column sums
__global__ void k_softmax(const __fp16* __restrict__ partial,
                          const float* __restrict__ encb,
                          float* __restrict__ colsum_parts) {
    __shared__ float red[4][64];
    const int lane = threadIdx.x & 63;
    const int wv   = threadIdx.x >> 6;
    const float eb = encb[lane];
    float accq = 0.f;
    for (int i = 0; i < 8; ++i) {
        const int r = blockIdx.x * 32 + i * 4 + wv;
        float x = eb;
#pragma unroll
        for (int ks = 0; ks < KSPLIT; ++ks)
            x += (float)partial[(size_t)ks * (B_DIM * Q_DIM) + (size_t)r * Q_DIM + lane];
        float m = x;
        for (int o = 32; o > 0; o >>= 1) m = fmaxf(m, __shfl_xor(m, o));
        float e = __expf(x - m);
        float s = e;
        for (int o = 32; o > 0; o >>= 1) s += __shfl_xor(s, o);
        accq += e / s;
    }
    red[wv][lane] = accq;
    __syncthreads();
    if (threadIdx.x < 64) {
        colsum_parts[blockIdx.x * 64 + lane] =
            red[0][lane] + red[1][lane] + red[2][lane] + red[3][lane];
    }
}

// k_final: 256 blocks; redundant tail per block
__global__ void k_final(const float* __restrict__ colsum_parts,
                        const float* __restrict__ qp,
                        const float* __restrict__ WM,
                        const float* __restrict__ b1,
                        const float* __restrict__ w2, const float* __restrict__ b2,
                        float* __restrict__ out) {
    __shared__ float red[4][64];
    __shared__ float t0[64];
    __shared__ float cs[N_GATES], ss[N_GATES];
    __shared__ float pA[NCHUNK][64];
    __shared__ float pB[2][64];
    __shared__ float fv[64];
    __shared__ float gv[64];
    __shared__ float hl[64];
    const int t    = threadIdx.x;          // 256
    const int lane = t & 63;
    const int wv   = t >> 6;               // 0..3

    for (int g = t; g < N_GATES; g += 256) {
        float th = qp[g] * 0.5f;
        cs[g] = __cosf(th);
        ss[g] = __sinf(th);
    }
    {
        float c = 0.f;
#pragma unroll
        for (int i = 0; i < 64; ++i)
            c += colsum_parts[(size_t)(wv * 64 + i) * 64 + lane];
        red[wv][lane] = c;
    }
    __syncthreads();
    if (t < 64)
        t0[t] = red[0][t] + red[1][t] + red[2][t] + red[3][t];
    {
        float p = (lane == 0) ? 1.f : 0.f;
        const int g0 = wv * CHUNK;
        for (int g = 0; g < CHUNK; ++g) {
            float prev = __shfl(p, (lane + 63) & 63);
            p = fmaf(cs[g0 + g], p, ss[g0 + g] * prev);
        }
        pA[wv][lane] = p;
    }
    __syncthreads();
    if (wv < 2) {
        float r = 0.f;
        for (int i = 0; i < 64; ++i)
            r += pA[2 * wv][i] * pA[2 * wv + 1][(lane - i) & 63];
        pB[wv][lane] = r;
    }
    __syncthreads();
    if (wv == 0) {
        float r = 0.f;
        for (int i = 0; i < 64; ++i)
            r += pB[0][i] * pB[1][(lane - i) & 63];
        fv[lane] = r;
    }
    __syncthreads();
    if (wv == 0) {
        float r = 0.f;
        for (int i = 0; i < 64; ++i)
            r += fv[i] * t0[(lane - i) & 63];
        gv[lane] = r;
    }
    __syncthreads();
    if (t < 64) {
        float v = 0.f;
        const float* wr = WM + (size_t)t * 64;
#pragma unroll
        for (int q = 0; q < 64; ++q)
            v = fmaf(wr[q], gv[q], v);
        hl[t] = fmaxf(v + b1[t], 0.f);
    }
    __syncthreads();
    const int a = blockIdx.x * 4 + wv;
    float v = w2[(size_t)a * H_DIM + lane] * hl[lane];
    for (int o = 32; o > 0; o >>= 1) v += __shfl_xor(v, o);
    if (lane == 0) out[a] = v + b2[a];
}

extern "C" void kernel_launch(void* const* d_in, const int* in_sizes, int n_in,
                              void* d_out, int out_size, void* d_ws, size_t ws_size,
                              hipStream_t stream) {
    const float* state = (const float*)d_in[0];
    const float* encw  = (const float*)d_in[1];
    const float* encb  = (const float*)d_in[2];
    const float* qp    = (const float*)d_in[3];
    const float* mo    = (const float*)d_in[4];
    const float* w1    = (const float*)d_in[5];
    const float* b1    = (const float*)d_in[6];
    const float* w2    = (const float*)d_in[7];
    const float* b2    = (const float*)d_in[8];
    float* out = (float*)d_out;

    float*  ws           = (float*)d_ws;
    float*  colsum_parts = ws;                             // 16384 floats (64 KB)
    __fp16* partial      = (__fp16*)(ws + 16384);          // 8*524288 f16 (8 MB)
    float*  WM           = ws + 16384 + (size_t)KSPLIT * B_DIM * Q_DIM / 2;  // 4096
    uint4*  bpack        = (uint4*)(WM + 4096);            // 65536 uint4 (1 MB)

    k_pre<<<dim3(320), dim3(256), 0, stream>>>(encw, bpack, w1, mo, WM);
    k_gemm<<<dim3(B_DIM / MT, KSPLIT), dim3(256), 0, stream>>>(state, bpack, partial);
    k_softmax<<<dim3(256), dim3(256), 0, stream>>>(partial, encb, colsum_parts);
    k_final<<<dim3(256), dim3(256), 0, stream>>>(colsum_parts, qp, WM, b1, w2, b2, out);
}